// Round 1
// baseline (76.474 us; speedup 1.0000x reference)
//
#include <hip/hip_runtime.h>

#define SEQ 200
#define DIM 512

// ---------------- Kernel A: global Frobenius-norm (sum of squares) ----------
__global__ __launch_bounds__(256) void ssq_kernel(const int* __restrict__ xs,
                                                  const float* __restrict__ freqs,
                                                  double* __restrict__ ssq,
                                                  int n) {
    double acc = 0.0;
    for (int i = blockIdx.x * blockDim.x + threadIdx.x; i < n;
         i += gridDim.x * blockDim.x) {
        float f = freqs[xs[i]];
        acc += (double)f * (double)f;
    }
    // wave (64-lane) reduce
    for (int off = 32; off > 0; off >>= 1)
        acc += __shfl_down(acc, off, 64);
    __shared__ double s_w[4];  // 256 threads = 4 waves
    int lane = threadIdx.x & 63;
    int wave = threadIdx.x >> 6;
    if (lane == 0) s_w[wave] = acc;
    __syncthreads();
    if (threadIdx.x == 0) {
        double t = s_w[0] + s_w[1] + s_w[2] + s_w[3];
        atomicAdd(ssq, t);
    }
}

// ---------------- Kernel B: scaled gather-pool -------------------------------
// One block per batch row b. 512 threads = 4 groups x 128 lanes.
// Each lane owns one float4 (16B) slice of the 512-wide embedding row.
// Group g handles l = g, g+4, g+8, ... ; partials combined via LDS.
__global__ __launch_bounds__(512) void pool_kernel(const int* __restrict__ xs,
                                                   const float* __restrict__ W,
                                                   const float* __restrict__ freqs,
                                                   const double* __restrict__ ssq,
                                                   float* __restrict__ out) {
    __shared__ int   s_idx[SEQ];
    __shared__ float s_scl[SEQ];
    __shared__ float s_part[3][DIM];  // partials for groups 1..3

    const int b   = blockIdx.x;
    const int tid = threadIdx.x;

    const float inv_norm = (float)(1.0 / sqrt(ssq[0]));

    // stage indices + scales for this row into LDS
    for (int l = tid; l < SEQ; l += 512) {
        int idx  = xs[b * SEQ + l];
        s_idx[l] = idx;
        s_scl[l] = freqs[idx] * inv_norm;
    }
    __syncthreads();

    const int group   = tid >> 7;    // 0..3
    const int lane128 = tid & 127;   // float4 slice id
    const int col4    = lane128 * 4;

    float4 acc = make_float4(0.f, 0.f, 0.f, 0.f);

    #pragma unroll 2
    for (int l = group; l < SEQ; l += 4) {
        const int   idx = s_idx[l];
        const float s   = s_scl[l];
        const float4 w  = *reinterpret_cast<const float4*>(
            W + (size_t)idx * DIM + col4);
        acc.x += s * w.x;
        acc.y += s * w.y;
        acc.z += s * w.z;
        acc.w += s * w.w;
    }

    if (group > 0)
        *reinterpret_cast<float4*>(&s_part[group - 1][col4]) = acc;
    __syncthreads();

    if (group == 0) {
        for (int g = 0; g < 3; ++g) {
            const float4 p = *reinterpret_cast<const float4*>(&s_part[g][col4]);
            acc.x += p.x; acc.y += p.y; acc.z += p.z; acc.w += p.w;
        }
        *reinterpret_cast<float4*>(out + (size_t)b * DIM + col4) = acc;
    }
}

extern "C" void kernel_launch(void* const* d_in, const int* in_sizes, int n_in,
                              void* d_out, int out_size, void* d_ws, size_t ws_size,
                              hipStream_t stream) {
    const int*   xs    = (const int*)d_in[0];    // [1024, 200] int32
    const float* W     = (const float*)d_in[1];  // [100000, 512] f32
    const float* freqs = (const float*)d_in[2];  // [100000] f32
    float* out = (float*)d_out;                  // [1024, 512] f32
    double* ssq = (double*)d_ws;

    const int n = in_sizes[0];          // 204800
    const int bsz = n / SEQ;            // 1024

    hipMemsetAsync(d_ws, 0, sizeof(double), stream);
    ssq_kernel<<<400, 256, 0, stream>>>(xs, freqs, ssq, n);
    pool_kernel<<<bsz, 512, 0, stream>>>(xs, W, freqs, ssq, out);
}